// Round 3
// baseline (124.694 us; speedup 1.0000x reference)
//
#include <hip/hip_runtime.h>
#include <hip/hip_bf16.h>

#define SCALE 0.044194173824159216f

typedef float f32x4 __attribute__((ext_vector_type(4)));
typedef __bf16 bf16x8 __attribute__((ext_vector_type(8)));

static __device__ __forceinline__ unsigned short f2bf(float f){
  unsigned u = __builtin_bit_cast(unsigned, f);
  u += 0x7fffu + ((u >> 16) & 1u);
  return (unsigned short)(u >> 16);
}

// kA: blocks 0..63: pack w1q|w1k|w1v transposed -> W1T bf16 [192][512]; w2q -> W2qT bf16 [512][64]
//     blocks 64..80: P = scale * Wq~ @ Wk~^T [65][65]
__global__ __launch_bounds__(256) void kA(const float* __restrict__ w1q, const float* __restrict__ w1k,
    const float* __restrict__ w1v, const float* __restrict__ w2q, const float* __restrict__ b2q,
    const float* __restrict__ w2k, const float* __restrict__ b2k,
    unsigned short* __restrict__ W1T, unsigned short* __restrict__ W2qT, float* __restrict__ Pm){
  const int bid = blockIdx.x, t = threadIdx.x;
  if (bid < 64){
    #pragma unroll
    for (int s = 0; s < 8; s++){
      int id = s*16384 + bid*256 + t;
      if (id < 192*512){
        int n = id >> 9, k = id & 511;
        int p = n >> 6, c = n & 63;
        const float* w1 = (p==0)? w1q : ((p==1)? w1k : w1v);
        W1T[id] = f2bf(w1[k*64 + c]);
      } else {
        int j = id - 192*512;
        int e = j >> 6, r = j & 63;
        W2qT[j] = f2bf(w2q[r*512 + e]);
      }
    }
  } else {
    int id = (bid - 64)*256 + t;
    if (id >= 65*65) return;
    int i = id / 65, j = id - i*65;
    const float* qi = (i < 64)? (w2q + i*512) : b2q;
    const float* kj = (j < 64)? (w2k + j*512) : b2k;
    float s = 0.f;
    for (int e = 0; e < 512; e += 4){
      float4 a = *(const float4*)(qi + e);
      float4 b = *(const float4*)(kj + e);
      s += a.x*b.x; s += a.y*b.y; s += a.z*b.z; s += a.w*b.w;
    }
    Pm[id] = s * SCALE;
  }
}

// kB: H = x@w1+b1 (q,k,v) via MFMA; Hq -> global bf16; Hk*m,Hv -> LDS fp32;
//     then partial Atil (65x65) for this 64-row chunk -> part[b][ch][4225] contiguous.
__global__ __launch_bounds__(256) void kB(const float* __restrict__ x, const unsigned short* __restrict__ W1T,
    const float* __restrict__ b1q, const float* __restrict__ b1k, const float* __restrict__ b1v,
    const int* __restrict__ mask,
    unsigned short* __restrict__ Hq, float* __restrict__ part){
  __shared__ __attribute__((aligned(16))) char smem[33792];
  unsigned short (*Ax)[40] = (unsigned short(*)[40])smem;          // [64][40] bf16 (GEMM phase)
  unsigned short (*Bt)[40] = (unsigned short(*)[40])(smem + 5120); // [192][40] bf16 (GEMM phase)
  float (*ak)[66] = (float(*)[66])smem;                            // [64][66] fp32 (Atil phase)
  float (*av)[66] = (float(*)[66])(smem + 16896);                  // [64][66] fp32 (Atil phase)
  const int t = threadIdx.x;
  const int lane = t & 63, wave = t >> 6;
  const int r0 = blockIdx.x * 64;
  f32x4 acc[12];
  #pragma unroll
  for (int j = 0; j < 12; j++) acc[j] = (f32x4){0.f,0.f,0.f,0.f};
  for (int k0 = 0; k0 < 512; k0 += 32){
    #pragma unroll
    for (int s = 0; s < 2; s++){           // stage A: 64 rows x 32 k (fp32->bf16)
      int i = t + 256*s;
      int r = i >> 3, kq = (i & 7) * 4;
      float4 v = *(const float4*)(x + (size_t)(r0 + r)*512 + k0 + kq);
      ushort4 pk; pk.x = f2bf(v.x); pk.y = f2bf(v.y); pk.z = f2bf(v.z); pk.w = f2bf(v.w);
      *(ushort4*)&Ax[r][kq] = pk;
    }
    #pragma unroll
    for (int s = 0; s < 3; s++){           // stage B: 192 cols x 32 k (bf16 n-major)
      int i = t + 256*s;
      int n = i >> 2, kq = (i & 3) * 8;
      *(uint4*)&Bt[n][kq] = *(const uint4*)(W1T + n*512 + k0 + kq);
    }
    __syncthreads();
    const int arow = (wave << 4) | (lane & 15);
    const int ks = (lane >> 4) * 8;
    bf16x8 af = *(const bf16x8*)&Ax[arow][ks];
    #pragma unroll
    for (int j = 0; j < 12; j++){
      bf16x8 bf = *(const bf16x8*)&Bt[j*16 + (lane & 15)][ks];
      acc[j] = __builtin_amdgcn_mfma_f32_16x16x32_bf16(af, bf, acc[j], 0, 0, 0);
    }
    __syncthreads();
  }
  // epilogue: Hq -> global, ak/av -> LDS (overwrites Ax/Bt, safe after final barrier)
  const int l15 = lane & 15, lg = lane >> 4;
  int rowl[4]; float mrow[4];
  #pragma unroll
  for (int rg = 0; rg < 4; rg++){
    rowl[rg] = (wave << 4) + (lg << 2) + rg;
    mrow[rg] = (float)mask[r0 + rowl[rg]];
  }
  #pragma unroll
  for (int j = 0; j < 4; j++){             // q -> global bf16
    int c = (j << 4) | l15;
    float bias = b1q[c];
    #pragma unroll
    for (int rg = 0; rg < 4; rg++)
      Hq[(size_t)(r0 + rowl[rg])*64 + c] = f2bf(acc[j][rg] + bias);
  }
  #pragma unroll
  for (int j = 0; j < 4; j++){             // k*m -> LDS fp32
    int c = (j << 4) | l15;
    float bias = b1k[c];
    #pragma unroll
    for (int rg = 0; rg < 4; rg++)
      ak[rowl[rg]][c] = (acc[4 + j][rg] + bias) * mrow[rg];
  }
  #pragma unroll
  for (int j = 0; j < 4; j++){             // v -> LDS fp32
    int c = (j << 4) | l15;
    float bias = b1v[c];
    #pragma unroll
    for (int rg = 0; rg < 4; rg++)
      av[rowl[rg]][c] = acc[8 + j][rg] + bias;
  }
  if (t < 64){ ak[t][64] = (float)mask[r0 + t]; av[t][64] = 1.f; }
  __syncthreads();
  // partial Atil: 13x13 threads, 5x5 register tiles over [65][65]
  if (t < 169){
    int tj = t / 13, ti = t - tj*13;
    int i0 = ti * 5, j0 = tj * 5;
    float pacc[5][5];
    #pragma unroll
    for (int a = 0; a < 5; a++)
      #pragma unroll
      for (int v = 0; v < 5; v++) pacc[a][v] = 0.f;
    for (int r = 0; r < 64; r++){
      float a[5], v[5];
      #pragma unroll
      for (int ii = 0; ii < 5; ii++) a[ii] = ak[r][i0 + ii];
      #pragma unroll
      for (int jj = 0; jj < 5; jj++) v[jj] = av[r][j0 + jj];
      #pragma unroll
      for (int ii = 0; ii < 5; ii++)
        #pragma unroll
        for (int jj = 0; jj < 5; jj++) pacc[ii][jj] += a[ii] * v[jj];
    }
    float* pout = part + (size_t)blockIdx.x * 4225;   // blockIdx = b*32+ch
    #pragma unroll
    for (int ii = 0; ii < 5; ii++)
      #pragma unroll
      for (int jj = 0; jj < 5; jj++)
        pout[(i0 + ii)*65 + (j0 + jj)] = pacc[ii][jj];
  }
}

// kC: reduce part -> Atl (LDS); T1 = P@Atl; G-chunk = T1@Wv~ -> GtA bf16 [b][512][64] + Gbias
// grid = 8 batches x 8 e-chunks of 64
__global__ __launch_bounds__(256) void kC(const float* __restrict__ part, const float* __restrict__ Pm,
    const float* __restrict__ w2v, const float* __restrict__ b2v,
    unsigned short* __restrict__ GtA, float* __restrict__ Gbias){
  __shared__ float Pl[65*66];
  __shared__ float Atl[65*66];
  __shared__ float T1l[65*66];
  const int t = threadIdx.x;
  const int b = blockIdx.x >> 3, ec = (blockIdx.x & 7) << 6;
  for (int id = t; id < 4225; id += 256){
    int i = id / 65, j = id - i*65;
    Pl[i*66 + j] = Pm[id];
  }
  const float* pb = part + (size_t)b*32*4225;
  for (int e0 = 0; e0 < 4225; e0 += 256){   // coalesced 32-way reduce
    int e = e0 + t;
    if (e < 4225){
      float s = 0.f;
      #pragma unroll 8
      for (int ch = 0; ch < 32; ch++) s += pb[(size_t)ch*4225 + e];
      int i = e / 65, j = e - i*65;
      Atl[i*66 + j] = s;
    }
  }
  __syncthreads();
  if (t < 169){                              // T1 = P @ Atl, 5x5 tiles
    int tj = t / 13, ti = t - tj*13;
    int i0 = ti * 5, j0 = tj * 5;
    float acc[5][5];
    #pragma unroll
    for (int a = 0; a < 5; a++)
      #pragma unroll
      for (int v = 0; v < 5; v++) acc[a][v] = 0.f;
    for (int k = 0; k < 65; k++){
      float a[5], vv[5];
      #pragma unroll
      for (int ii = 0; ii < 5; ii++) a[ii] = Pl[(i0 + ii)*66 + k];
      #pragma unroll
      for (int jj = 0; jj < 5; jj++) vv[jj] = Atl[k*66 + j0 + jj];
      #pragma unroll
      for (int ii = 0; ii < 5; ii++)
        #pragma unroll
        for (int jj = 0; jj < 5; jj++) acc[ii][jj] += a[ii] * vv[jj];
    }
    #pragma unroll
    for (int ii = 0; ii < 5; ii++)
      #pragma unroll
      for (int jj = 0; jj < 5; jj++) T1l[(i0 + ii)*66 + (j0 + jj)] = acc[ii][jj];
  }
  __syncthreads();
  for (int id = t; id < 4096; id += 256){    // stage Wv chunk into Pl (reuse)
    int j = id >> 6, c = id & 63;
    Pl[j*66 + c] = w2v[j*512 + ec + c];
  }
  __syncthreads();
  if (t < 169){                              // G = T1 @ Wl (+bias row), 5x5 tiles, e clamp
    int tj = t / 13, ti = t - tj*13;
    int i0 = ti * 5, j0 = tj * 5;
    float acc[5][5];
    #pragma unroll
    for (int a = 0; a < 5; a++)
      #pragma unroll
      for (int v = 0; v < 5; v++) acc[a][v] = 0.f;
    for (int k = 0; k < 64; k++){
      float a[5], vv[5];
      #pragma unroll
      for (int ii = 0; ii < 5; ii++) a[ii] = T1l[(i0 + ii)*66 + k];
      #pragma unroll
      for (int jj = 0; jj < 5; jj++) vv[jj] = Pl[k*66 + j0 + jj];
      #pragma unroll
      for (int ii = 0; ii < 5; ii++)
        #pragma unroll
        for (int jj = 0; jj < 5; jj++) acc[ii][jj] += a[ii] * vv[jj];
    }
    #pragma unroll
    for (int ii = 0; ii < 5; ii++){
      int r = i0 + ii;
      float t64 = T1l[r*66 + 64];
      #pragma unroll
      for (int jj = 0; jj < 5; jj++){
        int ej = j0 + jj;
        if (ej < 64){
          int e = ec + ej;
          float s = acc[ii][jj] + t64 * b2v[e];
          if (r < 64) GtA[((size_t)b*512 + e)*64 + r] = f2bf(s);
          else        Gbias[b*512 + e] = s;
        }
      }
    }
  }
}

// kD: zero-LDS, zero-barrier. temp = m*(hq@G + Gbias) -> softmax -> out; q = hq@W2q~ -> qout.
// A and B MFMA fragments read directly from global (L1/L2 resident B; full-line use via lg-group tiling).
__global__ __launch_bounds__(256) void kD(const unsigned short* __restrict__ Hq, const unsigned short* __restrict__ W2qT,
    const unsigned short* __restrict__ GtA, const float* __restrict__ Gbias, const float* __restrict__ b2q,
    const int* __restrict__ mask, float* __restrict__ out, float* __restrict__ qout){
  const int t = threadIdx.x, lane = t & 63, wave = t >> 6;
  const int b = blockIdx.x >> 5, rc = (blockIdx.x & 31) << 6;
  const int l15 = lane & 15, lg = lane >> 4, ks = lg * 8;
  const size_t gr0 = (size_t)b*2048 + rc;
  const int arow = (wave << 4) | l15;
  const unsigned short* arp = Hq + (gr0 + arow)*64 + ks;
  bf16x8 a0 = *(const bf16x8*)arp;
  bf16x8 a1 = *(const bf16x8*)(arp + 32);
  const unsigned short* Bsrc = GtA + (size_t)b*512*64;
  f32x4 acc[32];
  #pragma unroll
  for (int f = 0; f < 32; f++) acc[f] = (f32x4){0.f,0.f,0.f,0.f};
  #pragma unroll
  for (int f = 0; f < 32; f++){
    int col = (f << 4) | l15;
    bf16x8 b0 = *(const bf16x8*)(Bsrc + col*64 + ks);
    bf16x8 b1 = *(const bf16x8*)(Bsrc + col*64 + 32 + ks);
    acc[f] = __builtin_amdgcn_mfma_f32_16x16x32_bf16(a0, b0, acc[f], 0, 0, 0);
    acc[f] = __builtin_amdgcn_mfma_f32_16x16x32_bf16(a1, b1, acc[f], 0, 0, 0);
  }
  #pragma unroll
  for (int f = 0; f < 32; f++){
    float gbv = Gbias[(b << 9) | (f << 4) | l15];
    #pragma unroll
    for (int rg = 0; rg < 4; rg++) acc[f][rg] += gbv;
  }
  #pragma unroll
  for (int rg = 0; rg < 4; rg++){
    int row = rc + (wave << 4) + (lg << 2) + rg;
    float m = (float)mask[b*2048 + row];
    float mx = -3.4e38f;
    #pragma unroll
    for (int f = 0; f < 32; f++){
      float v = acc[f][rg] * m;
      acc[f][rg] = v;
      mx = fmaxf(mx, v);
    }
    #pragma unroll
    for (int d = 1; d < 16; d <<= 1) mx = fmaxf(mx, __shfl_xor(mx, d, 64));
    float sum = 0.f;
    #pragma unroll
    for (int f = 0; f < 32; f++){
      float ev = __expf(acc[f][rg] - mx);
      acc[f][rg] = ev;
      sum += ev;
    }
    #pragma unroll
    for (int d = 1; d < 16; d <<= 1) sum += __shfl_xor(sum, d, 64);
    float inv = 1.f / sum;
    float* orow = out + ((size_t)b*2048 + row) * 512;
    #pragma unroll
    for (int f = 0; f < 32; f++) orow[(f << 4) | l15] = acc[f][rg] * inv;
  }
  #pragma unroll
  for (int f = 0; f < 32; f++) acc[f] = (f32x4){0.f,0.f,0.f,0.f};
  #pragma unroll
  for (int f = 0; f < 32; f++){
    int col = (f << 4) | l15;
    bf16x8 b0 = *(const bf16x8*)(W2qT + col*64 + ks);
    bf16x8 b1 = *(const bf16x8*)(W2qT + col*64 + 32 + ks);
    acc[f] = __builtin_amdgcn_mfma_f32_16x16x32_bf16(a0, b0, acc[f], 0, 0, 0);
    acc[f] = __builtin_amdgcn_mfma_f32_16x16x32_bf16(a1, b1, acc[f], 0, 0, 0);
  }
  #pragma unroll
  for (int f = 0; f < 32; f++){
    int col = (f << 4) | l15;
    float bias = b2q[col];
    #pragma unroll
    for (int rg = 0; rg < 4; rg++){
      int row = rc + (wave << 4) + (lg << 2) + rg;
      qout[((size_t)b*2048 + row) * 512 + col] = acc[f][rg] + bias;
    }
  }
}

extern "C" void kernel_launch(void* const* d_in, const int* in_sizes, int n_in,
                              void* d_out, int out_size, void* d_ws, size_t ws_size,
                              hipStream_t stream){
  const float* x    = (const float*)d_in[0];
  const int*   mask = (const int*)d_in[1];
  const float* q_w1 = (const float*)d_in[2];
  const float* q_b1 = (const float*)d_in[3];
  const float* q_w2 = (const float*)d_in[4];
  const float* q_b2 = (const float*)d_in[5];
  const float* k_w1 = (const float*)d_in[6];
  const float* k_b1 = (const float*)d_in[7];
  const float* k_w2 = (const float*)d_in[8];
  const float* k_b2 = (const float*)d_in[9];
  const float* v_w1 = (const float*)d_in[10];
  const float* v_b1 = (const float*)d_in[11];
  const float* v_w2 = (const float*)d_in[12];
  const float* v_b2 = (const float*)d_in[13];

  char* ws = (char*)d_ws;
  unsigned short* W1T  = (unsigned short*)(ws + 0);        // 196608
  unsigned short* W2qT = (unsigned short*)(ws + 196608);   // 65536
  float*          Pm   = (float*)(ws + 262144);            // 16900 -> pad 17152
  unsigned short* Hq   = (unsigned short*)(ws + 279296);   // 2097152
  float*          part = (float*)(ws + 2376448);           // 8*32*4225*4 = 4326400
  unsigned short* GtA  = (unsigned short*)(ws + 6702848);  // 524288
  float*          Gbias= (float*)(ws + 7227136);           // 16384

  float* out  = (float*)d_out;
  float* qout = out + (size_t)8*2048*512;

  kA<<<81,  256, 0, stream>>>(q_w1, k_w1, v_w1, q_w2, q_b2, k_w2, k_b2, W1T, W2qT, Pm);
  kB<<<256, 256, 0, stream>>>(x, W1T, q_b1, k_b1, v_b1, mask, Hq, part);
  kC<<<64,  256, 0, stream>>>(part, Pm, v_w2, v_b2, GtA, Gbias);
  kD<<<256, 256, 0, stream>>>(Hq, W2qT, GtA, Gbias, q_b2, mask, out, qout);
}

// Round 5
// 107.459 us; speedup vs baseline: 1.1604x; 1.1604x over previous
//
#include <hip/hip_runtime.h>
#include <hip/hip_bf16.h>

#define SCALE 0.044194173824159216f

typedef float f32x4 __attribute__((ext_vector_type(4)));
typedef __bf16 bf16x8 __attribute__((ext_vector_type(8)));

static __device__ __forceinline__ unsigned short f2bf(float f){
  unsigned u = __builtin_bit_cast(unsigned, f);
  u += 0x7fffu + ((u >> 16) & 1u);
  return (unsigned short)(u >> 16);
}

// kB2: H = x@w1+b1 (q,k,v) via MFMA with self-staged transposed weights (no kA dispatch);
//      Hq -> global bf16; per-chunk partial Atil -> part[bid][4225] (chunk-major).
//      Side tasks: blocks 0..16 compute Pm; blocks 128..255 compute W2qT.
__global__ __launch_bounds__(256) void kB2(const float* __restrict__ x, const int* __restrict__ mask,
    const float* __restrict__ w1q, const float* __restrict__ b1q,
    const float* __restrict__ w1k, const float* __restrict__ b1k,
    const float* __restrict__ w1v, const float* __restrict__ b1v,
    const float* __restrict__ w2q, const float* __restrict__ b2q,
    const float* __restrict__ w2k, const float* __restrict__ b2k,
    unsigned short* __restrict__ Hq, float* __restrict__ part,
    float* __restrict__ Pm, unsigned short* __restrict__ W2qT){
  __shared__ __attribute__((aligned(16))) char smem[33792];
  unsigned short (*Ax)[40] = (unsigned short(*)[40])smem;          // [64][40] bf16 (GEMM phase)
  unsigned short (*Bt)[40] = (unsigned short(*)[40])(smem + 5120); // [192][40] bf16 (GEMM phase)
  float (*ak)[66] = (float(*)[66])smem;                            // [64][66] fp32 (Atil phase)
  float (*av)[66] = (float(*)[66])(smem + 16896);                  // [64][66] fp32 (Atil phase)
  const int t = threadIdx.x, bid = blockIdx.x;
  const int lane = t & 63, wave = t >> 6;
  const int l15 = lane & 15, lg = lane >> 4, ks = lg * 8;
  const int r0 = bid * 64;
  f32x4 acc[12];
  #pragma unroll
  for (int j = 0; j < 12; j++) acc[j] = (f32x4){0.f,0.f,0.f,0.f};
  for (int k0 = 0; k0 < 512; k0 += 32){
    #pragma unroll
    for (int s = 0; s < 2; s++){           // stage A: 64 rows x 32 k (fp32->bf16)
      int i = t + 256*s;
      int r = i >> 3, kq = (i & 7) * 4;
      float4 v = *(const float4*)(x + (size_t)(r0 + r)*512 + k0 + kq);
      ushort4 pk; pk.x = f2bf(v.x); pk.y = f2bf(v.y); pk.z = f2bf(v.z); pk.w = f2bf(v.w);
      *(ushort4*)&Ax[r][kq] = pk;
    }
    #pragma unroll
    for (int s = 0; s < 6; s++){           // stage B: transpose w1 from global (L2-resident)
      int id = t + 256*s;                  // 0..1535 = 32 kk x 48 c4-groups
      int kk = id / 48, g = id - kk*48;
      int p = g >> 4, c4 = (g & 15) << 2;
      const float* w1p = (p==0)? w1q : ((p==1)? w1k : w1v);
      float4 v = *(const float4*)(w1p + (k0 + kk)*64 + c4);
      int n = (p << 6) | c4;
      Bt[n][kk]     = f2bf(v.x);
      Bt[n + 1][kk] = f2bf(v.y);
      Bt[n + 2][kk] = f2bf(v.z);
      Bt[n + 3][kk] = f2bf(v.w);
    }
    __syncthreads();
    const int arow = (wave << 4) | l15;
    bf16x8 af = *(const bf16x8*)&Ax[arow][ks];
    #pragma unroll
    for (int j = 0; j < 12; j++){
      bf16x8 bf = *(const bf16x8*)&Bt[j*16 + l15][ks];
      acc[j] = __builtin_amdgcn_mfma_f32_16x16x32_bf16(af, bf, acc[j], 0, 0, 0);
    }
    __syncthreads();
  }
  // epilogue: Hq -> global, ak/av -> LDS (after final barrier)
  int rowl[4]; float mrow[4];
  #pragma unroll
  for (int rg = 0; rg < 4; rg++){
    rowl[rg] = (wave << 4) + (lg << 2) + rg;
    mrow[rg] = (float)mask[r0 + rowl[rg]];
  }
  #pragma unroll
  for (int j = 0; j < 4; j++){             // q -> global bf16
    int c = (j << 4) | l15;
    float bias = b1q[c];
    #pragma unroll
    for (int rg = 0; rg < 4; rg++)
      Hq[(size_t)(r0 + rowl[rg])*64 + c] = f2bf(acc[j][rg] + bias);
  }
  #pragma unroll
  for (int j = 0; j < 4; j++){             // k*m -> LDS fp32
    int c = (j << 4) | l15;
    float bias = b1k[c];
    #pragma unroll
    for (int rg = 0; rg < 4; rg++)
      ak[rowl[rg]][c] = (acc[4 + j][rg] + bias) * mrow[rg];
  }
  #pragma unroll
  for (int j = 0; j < 4; j++){             // v -> LDS fp32
    int c = (j << 4) | l15;
    float bias = b1v[c];
    #pragma unroll
    for (int rg = 0; rg < 4; rg++)
      av[rowl[rg]][c] = acc[8 + j][rg] + bias;
  }
  if (t < 64){ ak[t][64] = (float)mask[r0 + t]; av[t][64] = 1.f; }
  __syncthreads();
  if (t < 169){                            // partial Atil: 13x13 threads, 5x5 tiles
    int tj = t / 13, ti = t - tj*13;
    int i0 = ti * 5, j0 = tj * 5;
    float pacc[5][5];
    #pragma unroll
    for (int a = 0; a < 5; a++)
      #pragma unroll
      for (int v = 0; v < 5; v++) pacc[a][v] = 0.f;
    for (int r = 0; r < 64; r++){
      float a[5], v[5];
      #pragma unroll
      for (int ii = 0; ii < 5; ii++) a[ii] = ak[r][i0 + ii];
      #pragma unroll
      for (int jj = 0; jj < 5; jj++) v[jj] = av[r][j0 + jj];
      #pragma unroll
      for (int ii = 0; ii < 5; ii++)
        #pragma unroll
        for (int jj = 0; jj < 5; jj++) pacc[ii][jj] += a[ii] * v[jj];
    }
    float* pout = part + (size_t)bid * 4225;
    #pragma unroll
    for (int ii = 0; ii < 5; ii++)
      #pragma unroll
      for (int jj = 0; jj < 5; jj++)
        pout[(i0 + ii)*65 + (j0 + jj)] = pacc[ii][jj];
  }
  // side task 1: Pm on blocks 0..16
  if (bid < 17){
    int id2 = bid*256 + t;
    if (id2 < 4225){
      int i = id2 / 65, j = id2 - i*65;
      const float* qi = (i < 64)? (w2q + i*512) : b2q;
      const float* kj = (j < 64)? (w2k + j*512) : b2k;
      float s = 0.f;
      for (int e = 0; e < 512; e += 4){
        float4 a = *(const float4*)(qi + e);
        float4 b = *(const float4*)(kj + e);
        s += a.x*b.x + a.y*b.y + a.z*b.z + a.w*b.w;
      }
      Pm[id2] = s * SCALE;
    }
  }
  // side task 2: W2qT on blocks 128..255
  if (bid >= 128){
    int id3 = (bid - 128)*256 + t;        // 0..32767
    int e = id3 >> 6, r = id3 & 63;
    W2qT[id3] = f2bf(w2q[r*512 + e]);
  }
}

// kR: wide coalesced 32-way reduce part -> At[8][4225]
__global__ __launch_bounds__(256) void kR(const float* __restrict__ part, float* __restrict__ At){
  int g = blockIdx.x*256 + threadIdx.x;
  if (g < 33800){
    int b = g / 4225, e = g - b*4225;
    const float* p = part + (size_t)b*135200 + e;
    float s = 0.f;
    #pragma unroll
    for (int ch = 0; ch < 32; ch++) s += p[(size_t)ch*4225];
    At[g] = s;
  }
}

// k3b: T1 = P@At; G-chunk = T1@Wv~ -> GtA bf16 [b][512][64] + Gbias. grid = 8 b x 8 e-chunks
__global__ __launch_bounds__(256) void k3b(const float* __restrict__ At, const float* __restrict__ Pm,
    const float* __restrict__ w2v, const float* __restrict__ b2v,
    unsigned short* __restrict__ GtA, float* __restrict__ Gbias){
  __shared__ float Pl[65*66];
  __shared__ float Atl[65*66];
  __shared__ float T1l[65*66];
  const int t = threadIdx.x;
  const int b = blockIdx.x >> 3, ec = (blockIdx.x & 7) << 6;
  for (int id = t; id < 4225; id += 256){
    int i = id / 65, j = id - i*65;
    Pl[i*66 + j]  = Pm[id];
    Atl[i*66 + j] = At[(size_t)b*4225 + id];
  }
  __syncthreads();
  if (t < 169){                              // T1 = P @ Atl, 5x5 tiles
    int tj = t / 13, ti = t - tj*13;
    int i0 = ti * 5, j0 = tj * 5;
    float acc[5][5];
    #pragma unroll
    for (int a = 0; a < 5; a++)
      #pragma unroll
      for (int v = 0; v < 5; v++) acc[a][v] = 0.f;
    for (int k = 0; k < 65; k++){
      float a[5], vv[5];
      #pragma unroll
      for (int ii = 0; ii < 5; ii++) a[ii] = Pl[(i0 + ii)*66 + k];
      #pragma unroll
      for (int jj = 0; jj < 5; jj++) vv[jj] = Atl[k*66 + j0 + jj];
      #pragma unroll
      for (int ii = 0; ii < 5; ii++)
        #pragma unroll
        for (int jj = 0; jj < 5; jj++) acc[ii][jj] += a[ii] * vv[jj];
    }
    #pragma unroll
    for (int ii = 0; ii < 5; ii++)
      #pragma unroll
      for (int jj = 0; jj < 5; jj++) T1l[(i0 + ii)*66 + (j0 + jj)] = acc[ii][jj];
  }
  __syncthreads();
  for (int id = t; id < 4096; id += 256){    // stage Wv chunk into Pl (reuse)
    int j = id >> 6, c = id & 63;
    Pl[j*66 + c] = w2v[j*512 + ec + c];
  }
  __syncthreads();
  if (t < 169){                              // G = T1 @ Wl (+bias row)
    int tj = t / 13, ti = t - tj*13;
    int i0 = ti * 5, j0 = tj * 5;
    float acc[5][5];
    #pragma unroll
    for (int a = 0; a < 5; a++)
      #pragma unroll
      for (int v = 0; v < 5; v++) acc[a][v] = 0.f;
    for (int k = 0; k < 64; k++){
      float a[5], vv[5];
      #pragma unroll
      for (int ii = 0; ii < 5; ii++) a[ii] = T1l[(i0 + ii)*66 + k];
      #pragma unroll
      for (int jj = 0; jj < 5; jj++) vv[jj] = Pl[k*66 + j0 + jj];
      #pragma unroll
      for (int ii = 0; ii < 5; ii++)
        #pragma unroll
        for (int jj = 0; jj < 5; jj++) acc[ii][jj] += a[ii] * vv[jj];
    }
    #pragma unroll
    for (int ii = 0; ii < 5; ii++){
      int r = i0 + ii;
      float t64 = T1l[r*66 + 64];
      #pragma unroll
      for (int jj = 0; jj < 5; jj++){
        int ej = j0 + jj;
        if (ej < 64){
          int e = ec + ej;
          float s = acc[ii][jj] + t64 * b2v[e];
          if (r < 64) GtA[((size_t)b*512 + e)*64 + r] = f2bf(s);
          else        Gbias[b*512 + e] = s;
        }
      }
    }
  }
}

// kD: zero-LDS, zero-barrier. temp = m*(hq@G + Gbias) -> softmax -> out; q = hq@W2q~ -> qout.
__global__ __launch_bounds__(256) void kD(const unsigned short* __restrict__ Hq, const unsigned short* __restrict__ W2qT,
    const unsigned short* __restrict__ GtA, const float* __restrict__ Gbias, const float* __restrict__ b2q,
    const int* __restrict__ mask, float* __restrict__ out, float* __restrict__ qout){
  const int t = threadIdx.x, lane = t & 63, wave = t >> 6;
  const int b = blockIdx.x >> 5, rc = (blockIdx.x & 31) << 6;
  const int l15 = lane & 15, lg = lane >> 4, ks = lg * 8;
  const size_t gr0 = (size_t)b*2048 + rc;
  const int arow = (wave << 4) | l15;
  const unsigned short* arp = Hq + (gr0 + arow)*64 + ks;
  bf16x8 a0 = *(const bf16x8*)arp;
  bf16x8 a1 = *(const bf16x8*)(arp + 32);
  const unsigned short* Bsrc = GtA + (size_t)b*512*64;
  f32x4 acc[32];
  #pragma unroll
  for (int f = 0; f < 32; f++) acc[f] = (f32x4){0.f,0.f,0.f,0.f};
  #pragma unroll
  for (int f = 0; f < 32; f++){
    int col = (f << 4) | l15;
    bf16x8 b0 = *(const bf16x8*)(Bsrc + col*64 + ks);
    bf16x8 b1 = *(const bf16x8*)(Bsrc + col*64 + 32 + ks);
    acc[f] = __builtin_amdgcn_mfma_f32_16x16x32_bf16(a0, b0, acc[f], 0, 0, 0);
    acc[f] = __builtin_amdgcn_mfma_f32_16x16x32_bf16(a1, b1, acc[f], 0, 0, 0);
  }
  #pragma unroll
  for (int f = 0; f < 32; f++){
    float gbv = Gbias[(b << 9) | (f << 4) | l15];
    #pragma unroll
    for (int rg = 0; rg < 4; rg++) acc[f][rg] += gbv;
  }
  #pragma unroll
  for (int rg = 0; rg < 4; rg++){
    int row = rc + (wave << 4) + (lg << 2) + rg;
    float m = (float)mask[b*2048 + row];
    float mx = -3.4e38f;
    #pragma unroll
    for (int f = 0; f < 32; f++){
      float v = acc[f][rg] * m;
      acc[f][rg] = v;
      mx = fmaxf(mx, v);
    }
    #pragma unroll
    for (int d = 1; d < 16; d <<= 1) mx = fmaxf(mx, __shfl_xor(mx, d, 64));
    float sum = 0.f;
    #pragma unroll
    for (int f = 0; f < 32; f++){
      float ev = __expf(acc[f][rg] - mx);
      acc[f][rg] = ev;
      sum += ev;
    }
    #pragma unroll
    for (int d = 1; d < 16; d <<= 1) sum += __shfl_xor(sum, d, 64);
    float inv = 1.f / sum;
    float* orow = out + ((size_t)b*2048 + row) * 512;
    #pragma unroll
    for (int f = 0; f < 32; f++) orow[(f << 4) | l15] = acc[f][rg] * inv;
  }
  #pragma unroll
  for (int f = 0; f < 32; f++) acc[f] = (f32x4){0.f,0.f,0.f,0.f};
  #pragma unroll
  for (int f = 0; f < 32; f++){
    int col = (f << 4) | l15;
    bf16x8 b0 = *(const bf16x8*)(W2qT + col*64 + ks);
    bf16x8 b1 = *(const bf16x8*)(W2qT + col*64 + 32 + ks);
    acc[f] = __builtin_amdgcn_mfma_f32_16x16x32_bf16(a0, b0, acc[f], 0, 0, 0);
    acc[f] = __builtin_amdgcn_mfma_f32_16x16x32_bf16(a1, b1, acc[f], 0, 0, 0);
  }
  #pragma unroll
  for (int f = 0; f < 32; f++){
    int col = (f << 4) | l15;
    float bias = b2q[col];
    #pragma unroll
    for (int rg = 0; rg < 4; rg++){
      int row = rc + (wave << 4) + (lg << 2) + rg;
      qout[((size_t)b*2048 + row) * 512 + col] = acc[f][rg] + bias;
    }
  }
}

extern "C" void kernel_launch(void* const* d_in, const int* in_sizes, int n_in,
                              void* d_out, int out_size, void* d_ws, size_t ws_size,
                              hipStream_t stream){
  const float* x    = (const float*)d_in[0];
  const int*   mask = (const int*)d_in[1];
  const float* q_w1 = (const float*)d_in[2];
  const float* q_b1 = (const float*)d_in[3];
  const float* q_w2 = (const float*)d_in[4];
  const float* q_b2 = (const float*)d_in[5];
  const float* k_w1 = (const float*)d_in[6];
  const float* k_b1 = (const float*)d_in[7];
  const float* k_w2 = (const float*)d_in[8];
  const float* k_b2 = (const float*)d_in[9];
  const float* v_w1 = (const float*)d_in[10];
  const float* v_b1 = (const float*)d_in[11];
  const float* v_w2 = (const float*)d_in[12];
  const float* v_b2 = (const float*)d_in[13];

  char* ws = (char*)d_ws;
  float*          Pm   = (float*)(ws + 0);        // 16900 -> pad 32768
  unsigned short* W2qT = (unsigned short*)(ws + 32768);    // 65536 -> ends 98304
  unsigned short* Hq   = (unsigned short*)(ws + 98304);    // 2097152 -> ends 2195456
  float*          part = (float*)(ws + 2195456);  // 4326400 -> ends 6521856
  float*          At   = (float*)(ws + 6521856);  // 135200 -> pad ends 6657280
  unsigned short* GtA  = (unsigned short*)(ws + 6657280);  // 524288 -> ends 7181568
  float*          Gbias= (float*)(ws + 7181568);  // 16384

  float* out  = (float*)d_out;
  float* qout = out + (size_t)8*2048*512;

  kB2<<<256, 256, 0, stream>>>(x, mask, q_w1, q_b1, k_w1, k_b1, v_w1, v_b1,
                               q_w2, q_b2, k_w2, k_b2, Hq, part, Pm, W2qT);
  kR <<<133, 256, 0, stream>>>(part, At);
  k3b<<<64,  256, 0, stream>>>(At, Pm, v_w2, v_b2, GtA, Gbias);
  kD <<<256, 256, 0, stream>>>(Hq, W2qT, GtA, Gbias, q_b2, mask, out, qout);
}

// Round 6
// 89.959 us; speedup vs baseline: 1.3861x; 1.1945x over previous
//
#include <hip/hip_runtime.h>
#include <hip/hip_bf16.h>

#define SCALE 0.044194173824159216f

typedef float f32x4 __attribute__((ext_vector_type(4)));
typedef __bf16 bf16x8 __attribute__((ext_vector_type(8)));

static __device__ __forceinline__ unsigned short f2bf(float f){
  unsigned u = __builtin_bit_cast(unsigned, f);
  u += 0x7fffu + ((u >> 16) & 1u);
  return (unsigned short)(u >> 16);
}

// kA: blocks 0..63: pack w1q|w1k|w1v transposed -> W1T bf16 [192][512]; w2q -> W2qT bf16 [512][64]
//     blocks 64..80: P = scale * Wq~ @ Wk~^T [65][65]
__global__ __launch_bounds__(256) void kA(const float* __restrict__ w1q, const float* __restrict__ w1k,
    const float* __restrict__ w1v, const float* __restrict__ w2q, const float* __restrict__ b2q,
    const float* __restrict__ w2k, const float* __restrict__ b2k,
    unsigned short* __restrict__ W1T, unsigned short* __restrict__ W2qT, float* __restrict__ Pm){
  const int bid = blockIdx.x, t = threadIdx.x;
  if (bid < 64){
    #pragma unroll
    for (int s = 0; s < 8; s++){
      int id = s*16384 + bid*256 + t;
      if (id < 192*512){
        int n = id >> 9, k = id & 511;
        int p = n >> 6, c = n & 63;
        const float* w1 = (p==0)? w1q : ((p==1)? w1k : w1v);
        W1T[id] = f2bf(w1[k*64 + c]);
      } else {
        int j = id - 192*512;
        int e = j >> 6, r = j & 63;
        W2qT[j] = f2bf(w2q[r*512 + e]);
      }
    }
  } else {
    int id = (bid - 64)*256 + t;
    if (id >= 65*65) return;
    int i = id / 65, j = id - i*65;
    const float* qi = (i < 64)? (w2q + i*512) : b2q;
    const float* kj = (j < 64)? (w2k + j*512) : b2k;
    float s = 0.f;
    for (int e = 0; e < 512; e += 4){
      float4 a = *(const float4*)(qi + e);
      float4 b = *(const float4*)(kj + e);
      s += a.x*b.x; s += a.y*b.y; s += a.z*b.z; s += a.w*b.w;
    }
    Pm[id] = s * SCALE;
  }
}

// kB: H = x@w1+b1 (q,k,v) via MFMA; Hq -> global bf16; Hk*m,Hv -> LDS fp32;
//     then partial Atil (65x65) for this 64-row chunk -> part[bid][4225] contiguous.
__global__ __launch_bounds__(256) void kB(const float* __restrict__ x, const unsigned short* __restrict__ W1T,
    const float* __restrict__ b1q, const float* __restrict__ b1k, const float* __restrict__ b1v,
    const int* __restrict__ mask,
    unsigned short* __restrict__ Hq, float* __restrict__ part){
  __shared__ __attribute__((aligned(16))) char smem[33792];
  unsigned short (*Ax)[40] = (unsigned short(*)[40])smem;          // [64][40] bf16 (GEMM phase)
  unsigned short (*Bt)[40] = (unsigned short(*)[40])(smem + 5120); // [192][40] bf16 (GEMM phase)
  float (*ak)[66] = (float(*)[66])smem;                            // [64][66] fp32 (Atil phase)
  float (*av)[66] = (float(*)[66])(smem + 16896);                  // [64][66] fp32 (Atil phase)
  const int t = threadIdx.x;
  const int lane = t & 63, wave = t >> 6;
  const int l15 = lane & 15, lg = lane >> 4, ks = lg * 8;
  const int r0 = blockIdx.x * 64;
  f32x4 acc[12];
  #pragma unroll
  for (int j = 0; j < 12; j++) acc[j] = (f32x4){0.f,0.f,0.f,0.f};
  for (int k0 = 0; k0 < 512; k0 += 32){
    #pragma unroll
    for (int s = 0; s < 2; s++){           // stage A: 64 rows x 32 k (fp32->bf16)
      int i = t + 256*s;
      int r = i >> 3, kq = (i & 7) * 4;
      float4 v = *(const float4*)(x + (size_t)(r0 + r)*512 + k0 + kq);
      ushort4 pk; pk.x = f2bf(v.x); pk.y = f2bf(v.y); pk.z = f2bf(v.z); pk.w = f2bf(v.w);
      *(ushort4*)&Ax[r][kq] = pk;
    }
    #pragma unroll
    for (int s = 0; s < 3; s++){           // stage B: 192 cols x 32 k (bf16 n-major)
      int i = t + 256*s;
      int n = i >> 2, kq = (i & 3) * 8;
      *(uint4*)&Bt[n][kq] = *(const uint4*)(W1T + n*512 + k0 + kq);
    }
    __syncthreads();
    const int arow = (wave << 4) | l15;
    bf16x8 af = *(const bf16x8*)&Ax[arow][ks];
    #pragma unroll
    for (int j = 0; j < 12; j++){
      bf16x8 bf = *(const bf16x8*)&Bt[j*16 + l15][ks];
      acc[j] = __builtin_amdgcn_mfma_f32_16x16x32_bf16(af, bf, acc[j], 0, 0, 0);
    }
    __syncthreads();
  }
  // epilogue: Hq -> global, ak/av -> LDS (after final barrier)
  int rowl[4]; float mrow[4];
  #pragma unroll
  for (int rg = 0; rg < 4; rg++){
    rowl[rg] = (wave << 4) + (lg << 2) + rg;
    mrow[rg] = (float)mask[r0 + rowl[rg]];
  }
  #pragma unroll
  for (int j = 0; j < 4; j++){             // q -> global bf16
    int c = (j << 4) | l15;
    float bias = b1q[c];
    #pragma unroll
    for (int rg = 0; rg < 4; rg++)
      Hq[(size_t)(r0 + rowl[rg])*64 + c] = f2bf(acc[j][rg] + bias);
  }
  #pragma unroll
  for (int j = 0; j < 4; j++){             // k*m -> LDS fp32
    int c = (j << 4) | l15;
    float bias = b1k[c];
    #pragma unroll
    for (int rg = 0; rg < 4; rg++)
      ak[rowl[rg]][c] = (acc[4 + j][rg] + bias) * mrow[rg];
  }
  #pragma unroll
  for (int j = 0; j < 4; j++){             // v -> LDS fp32
    int c = (j << 4) | l15;
    float bias = b1v[c];
    #pragma unroll
    for (int rg = 0; rg < 4; rg++)
      av[rowl[rg]][c] = acc[8 + j][rg] + bias;
  }
  if (t < 64){ ak[t][64] = (float)mask[r0 + t]; av[t][64] = 1.f; }
  __syncthreads();
  if (t < 169){                            // partial Atil: 13x13 threads, 5x5 tiles
    int tj = t / 13, ti = t - tj*13;
    int i0 = ti * 5, j0 = tj * 5;
    float pacc[5][5];
    #pragma unroll
    for (int a = 0; a < 5; a++)
      #pragma unroll
      for (int v = 0; v < 5; v++) pacc[a][v] = 0.f;
    for (int r = 0; r < 64; r++){
      float a[5], v[5];
      #pragma unroll
      for (int ii = 0; ii < 5; ii++) a[ii] = ak[r][i0 + ii];
      #pragma unroll
      for (int jj = 0; jj < 5; jj++) v[jj] = av[r][j0 + jj];
      #pragma unroll
      for (int ii = 0; ii < 5; ii++)
        #pragma unroll
        for (int jj = 0; jj < 5; jj++) pacc[ii][jj] += a[ii] * v[jj];
    }
    float* pout = part + (size_t)blockIdx.x * 4225;
    #pragma unroll
    for (int ii = 0; ii < 5; ii++)
      #pragma unroll
      for (int jj = 0; jj < 5; jj++)
        pout[(i0 + ii)*65 + (j0 + jj)] = pacc[ii][jj];
  }
}

// kR: wide coalesced 32-way reduce part -> At[8][4225]
__global__ __launch_bounds__(256) void kR(const float* __restrict__ part, float* __restrict__ At){
  int g = blockIdx.x*256 + threadIdx.x;
  if (g < 33800){
    int b = g / 4225, e = g - b*4225;
    const float* p = part + (size_t)b*135200 + e;
    float s = 0.f;
    #pragma unroll
    for (int ch = 0; ch < 32; ch++) s += p[(size_t)ch*4225];
    At[g] = s;
  }
}

// k3b: T1 = P@At; G-chunk = T1@Wv~ -> GtA bf16 [b][512][64] + Gbias. grid = 8 b x 8 e-chunks
__global__ __launch_bounds__(256) void k3b(const float* __restrict__ At, const float* __restrict__ Pm,
    const float* __restrict__ w2v, const float* __restrict__ b2v,
    unsigned short* __restrict__ GtA, float* __restrict__ Gbias){
  __shared__ float Pl[65*66];
  __shared__ float Atl[65*66];
  __shared__ float T1l[65*66];
  const int t = threadIdx.x;
  const int b = blockIdx.x >> 3, ec = (blockIdx.x & 7) << 6;
  for (int id = t; id < 4225; id += 256){
    int i = id / 65, j = id - i*65;
    Pl[i*66 + j]  = Pm[id];
    Atl[i*66 + j] = At[(size_t)b*4225 + id];
  }
  __syncthreads();
  if (t < 169){                              // T1 = P @ Atl, 5x5 tiles
    int tj = t / 13, ti = t - tj*13;
    int i0 = ti * 5, j0 = tj * 5;
    float acc[5][5];
    #pragma unroll
    for (int a = 0; a < 5; a++)
      #pragma unroll
      for (int v = 0; v < 5; v++) acc[a][v] = 0.f;
    for (int k = 0; k < 65; k++){
      float a[5], vv[5];
      #pragma unroll
      for (int ii = 0; ii < 5; ii++) a[ii] = Pl[(i0 + ii)*66 + k];
      #pragma unroll
      for (int jj = 0; jj < 5; jj++) vv[jj] = Atl[k*66 + j0 + jj];
      #pragma unroll
      for (int ii = 0; ii < 5; ii++)
        #pragma unroll
        for (int jj = 0; jj < 5; jj++) acc[ii][jj] += a[ii] * vv[jj];
    }
    #pragma unroll
    for (int ii = 0; ii < 5; ii++)
      #pragma unroll
      for (int jj = 0; jj < 5; jj++) T1l[(i0 + ii)*66 + (j0 + jj)] = acc[ii][jj];
  }
  __syncthreads();
  for (int id = t; id < 4096; id += 256){    // stage Wv chunk into Pl (reuse)
    int j = id >> 6, c = id & 63;
    Pl[j*66 + c] = w2v[j*512 + ec + c];
  }
  __syncthreads();
  if (t < 169){                              // G = T1 @ Wl (+bias row)
    int tj = t / 13, ti = t - tj*13;
    int i0 = ti * 5, j0 = tj * 5;
    float acc[5][5];
    #pragma unroll
    for (int a = 0; a < 5; a++)
      #pragma unroll
      for (int v = 0; v < 5; v++) acc[a][v] = 0.f;
    for (int k = 0; k < 64; k++){
      float a[5], vv[5];
      #pragma unroll
      for (int ii = 0; ii < 5; ii++) a[ii] = T1l[(i0 + ii)*66 + k];
      #pragma unroll
      for (int jj = 0; jj < 5; jj++) vv[jj] = Pl[k*66 + j0 + jj];
      #pragma unroll
      for (int ii = 0; ii < 5; ii++)
        #pragma unroll
        for (int jj = 0; jj < 5; jj++) acc[ii][jj] += a[ii] * vv[jj];
    }
    #pragma unroll
    for (int ii = 0; ii < 5; ii++){
      int r = i0 + ii;
      float t64 = T1l[r*66 + 64];
      #pragma unroll
      for (int jj = 0; jj < 5; jj++){
        int ej = j0 + jj;
        if (ej < 64){
          int e = ec + ej;
          float s = acc[ii][jj] + t64 * b2v[e];
          if (r < 64) GtA[((size_t)b*512 + e)*64 + r] = f2bf(s);
          else        Gbias[b*512 + e] = s;
        }
      }
    }
  }
}

// kD: zero-LDS, zero-barrier. temp = m*(hq@G + Gbias) -> softmax -> out; q = hq@W2q~ -> qout.
__global__ __launch_bounds__(256) void kD(const unsigned short* __restrict__ Hq, const unsigned short* __restrict__ W2qT,
    const unsigned short* __restrict__ GtA, const float* __restrict__ Gbias, const float* __restrict__ b2q,
    const int* __restrict__ mask, float* __restrict__ out, float* __restrict__ qout){
  const int t = threadIdx.x, lane = t & 63, wave = t >> 6;
  const int b = blockIdx.x >> 5, rc = (blockIdx.x & 31) << 6;
  const int l15 = lane & 15, lg = lane >> 4, ks = lg * 8;
  const size_t gr0 = (size_t)b*2048 + rc;
  const int arow = (wave << 4) | l15;
  const unsigned short* arp = Hq + (gr0 + arow)*64 + ks;
  bf16x8 a0 = *(const bf16x8*)arp;
  bf16x8 a1 = *(const bf16x8*)(arp + 32);
  const unsigned short* Bsrc = GtA + (size_t)b*512*64;
  f32x4 acc[32];
  #pragma unroll
  for (int f = 0; f < 32; f++) acc[f] = (f32x4){0.f,0.f,0.f,0.f};
  #pragma unroll
  for (int f = 0; f < 32; f++){
    int col = (f << 4) | l15;
    bf16x8 b0 = *(const bf16x8*)(Bsrc + col*64 + ks);
    bf16x8 b1 = *(const bf16x8*)(Bsrc + col*64 + 32 + ks);
    acc[f] = __builtin_amdgcn_mfma_f32_16x16x32_bf16(a0, b0, acc[f], 0, 0, 0);
    acc[f] = __builtin_amdgcn_mfma_f32_16x16x32_bf16(a1, b1, acc[f], 0, 0, 0);
  }
  #pragma unroll
  for (int f = 0; f < 32; f++){
    float gbv = Gbias[(b << 9) | (f << 4) | l15];
    #pragma unroll
    for (int rg = 0; rg < 4; rg++) acc[f][rg] += gbv;
  }
  #pragma unroll
  for (int rg = 0; rg < 4; rg++){
    int row = rc + (wave << 4) + (lg << 2) + rg;
    float m = (float)mask[b*2048 + row];
    float mx = -3.4e38f;
    #pragma unroll
    for (int f = 0; f < 32; f++){
      float v = acc[f][rg] * m;
      acc[f][rg] = v;
      mx = fmaxf(mx, v);
    }
    #pragma unroll
    for (int d = 1; d < 16; d <<= 1) mx = fmaxf(mx, __shfl_xor(mx, d, 64));
    float sum = 0.f;
    #pragma unroll
    for (int f = 0; f < 32; f++){
      float ev = __expf(acc[f][rg] - mx);
      acc[f][rg] = ev;
      sum += ev;
    }
    #pragma unroll
    for (int d = 1; d < 16; d <<= 1) sum += __shfl_xor(sum, d, 64);
    float inv = 1.f / sum;
    float* orow = out + ((size_t)b*2048 + row) * 512;
    #pragma unroll
    for (int f = 0; f < 32; f++) orow[(f << 4) | l15] = acc[f][rg] * inv;
  }
  #pragma unroll
  for (int f = 0; f < 32; f++) acc[f] = (f32x4){0.f,0.f,0.f,0.f};
  #pragma unroll
  for (int f = 0; f < 32; f++){
    int col = (f << 4) | l15;
    bf16x8 b0 = *(const bf16x8*)(W2qT + col*64 + ks);
    bf16x8 b1 = *(const bf16x8*)(W2qT + col*64 + 32 + ks);
    acc[f] = __builtin_amdgcn_mfma_f32_16x16x32_bf16(a0, b0, acc[f], 0, 0, 0);
    acc[f] = __builtin_amdgcn_mfma_f32_16x16x32_bf16(a1, b1, acc[f], 0, 0, 0);
  }
  #pragma unroll
  for (int f = 0; f < 32; f++){
    int col = (f << 4) | l15;
    float bias = b2q[col];
    #pragma unroll
    for (int rg = 0; rg < 4; rg++){
      int row = rc + (wave << 4) + (lg << 2) + rg;
      qout[((size_t)b*2048 + row) * 512 + col] = acc[f][rg] + bias;
    }
  }
}

extern "C" void kernel_launch(void* const* d_in, const int* in_sizes, int n_in,
                              void* d_out, int out_size, void* d_ws, size_t ws_size,
                              hipStream_t stream){
  const float* x    = (const float*)d_in[0];
  const int*   mask = (const int*)d_in[1];
  const float* q_w1 = (const float*)d_in[2];
  const float* q_b1 = (const float*)d_in[3];
  const float* q_w2 = (const float*)d_in[4];
  const float* q_b2 = (const float*)d_in[5];
  const float* k_w1 = (const float*)d_in[6];
  const float* k_b1 = (const float*)d_in[7];
  const float* k_w2 = (const float*)d_in[8];
  const float* k_b2 = (const float*)d_in[9];
  const float* v_w1 = (const float*)d_in[10];
  const float* v_b1 = (const float*)d_in[11];
  const float* v_w2 = (const float*)d_in[12];
  const float* v_b2 = (const float*)d_in[13];

  char* ws = (char*)d_ws;
  unsigned short* W1T  = (unsigned short*)(ws + 0);        // 196608
  unsigned short* W2qT = (unsigned short*)(ws + 196608);   // 65536 -> 262144
  float*          Pm   = (float*)(ws + 262144);            // 16900 -> pad 279296
  unsigned short* Hq   = (unsigned short*)(ws + 279296);   // 2097152 -> 2376448
  float*          part = (float*)(ws + 2376448);           // 4326400 -> 6702848
  float*          At   = (float*)(ws + 6702848);           // 135200 -> pad 6838272
  unsigned short* GtA  = (unsigned short*)(ws + 6838272);  // 524288 -> 7362560
  float*          Gbias= (float*)(ws + 7362560);           // 16384

  float* out  = (float*)d_out;
  float* qout = out + (size_t)8*2048*512;

  kA <<<81,  256, 0, stream>>>(q_w1, k_w1, v_w1, q_w2, q_b2, k_w2, k_b2, W1T, W2qT, Pm);
  kB <<<256, 256, 0, stream>>>(x, W1T, q_b1, k_b1, v_b1, mask, Hq, part);
  kR <<<133, 256, 0, stream>>>(part, At);
  k3b<<<64,  256, 0, stream>>>(At, Pm, v_w2, v_b2, GtA, Gbias);
  kD <<<256, 256, 0, stream>>>(Hq, W2qT, GtA, Gbias, q_b2, mask, out, qout);
}